// Round 3
// baseline (4761.159 us; speedup 1.0000x reference)
//
#include <hip/hip_runtime.h>

// Residual VQ via bf16x3 split-MFMA: B=16, D=128, L=4096, K=8, N=1024.
// score GEMM runs on the matrix pipe as 6 bf16 plane-products:
//   a = a0+a1+a2 (bf16 RNE split), b likewise; keep {a0b0,a0b1,a1b0,a1b1,a0b2,a2b0}
//   -> 2 MFMA passes of K=384: pass1 A=[a0,a1,a2] B=[b0,b1,b0]; pass2 A=[a0,a0,a1] B=[b1,b2,b0]
// Error ~2^-24 rel, far under the fp32-reorder noise that already matched exactly.
//
// B planes pre-packed once (pack_b) into per-lane MFMA fragment order in d_ws:
// 12 unique (plane,quarter) slabs x 64 nfrag x 64 lanes x 16B = 6.0 MiB, L2-resident;
// K-loop loads B frags straight global->VGPR (coalesced, no LDS staging, no barriers).
// A planes (residual split) built per step in LDS in A-fragment layout.

#define BB 16
#define DD 128
#define LL 4096
#define KK 8
#define NN 1024

typedef __attribute__((ext_vector_type(8))) short bf16x8;
typedef __attribute__((ext_vector_type(4))) float f32x4;
typedef __attribute__((ext_vector_type(4))) unsigned int u32x4;

__device__ __forceinline__ unsigned short f2bf(float f) {  // RNE bf16
    unsigned u = __float_as_uint(f);
    unsigned r = u + 0x7FFFu + ((u >> 16) & 1u);
    return (unsigned short)(r >> 16);
}
__device__ __forceinline__ float bf2f(unsigned short h) {
    return __uint_as_float(((unsigned)h) << 16);
}

__global__ void cnorm_kernel(const float* __restrict__ cb, float* __restrict__ cnorm) {
    int row = blockIdx.x * blockDim.x + threadIdx.x;   // 0..K*N-1
    const float4* p = (const float4*)(cb + (size_t)row * DD);
    float s = 0.f;
#pragma unroll
    for (int i = 0; i < DD / 4; ++i) {
        float4 v = p[i];
        s += v.x * v.x + v.y * v.y + v.z * v.z + v.w * v.w;
    }
    cnorm[row] = s;
}

// Pack codebook bf16 planes into MFMA B-fragment order.
// Entry e = ((k*12 + slab)*64 + nf)*64 + lane ; slab = plane*4 + d_quarter.
// Lane holds B[d = q*32 + (lane>>4)*8 + j][n = nf*16 + (lane&15)], j=0..7.
__global__ void pack_b(const float* __restrict__ cb, u32x4* __restrict__ bp) {
    int e = blockIdx.x * 256 + threadIdx.x;       // 0 .. 8*12*4096-1
    int lane = e & 63;
    int nf   = (e >> 6) & 63;
    int rest = e >> 12;                           // k*12 + slab
    int slab = rest % 12;
    int k    = rest / 12;
    int p = slab >> 2, q = slab & 3;
    int n = nf * 16 + (lane & 15);
    int d0 = q * 32 + (lane >> 4) * 8;
    const float* row = cb + ((size_t)k * NN + n) * DD + d0;
    unsigned short h[8];
#pragma unroll
    for (int j = 0; j < 8; ++j) {
        float v = row[j];
        unsigned short c0 = f2bf(v); float f0 = bf2f(c0);
        float r1 = v - f0;
        unsigned short c1 = f2bf(r1); float f1 = bf2f(c1);
        unsigned short c2 = f2bf(r1 - f1);
        h[j] = (p == 0) ? c0 : (p == 1) ? c1 : c2;
    }
    u32x4 w;
    w.x = (unsigned)h[0] | ((unsigned)h[1] << 16);
    w.y = (unsigned)h[2] | ((unsigned)h[3] << 16);
    w.z = (unsigned)h[4] | ((unsigned)h[5] << 16);
    w.w = (unsigned)h[6] | ((unsigned)h[7] << 16);
    bp[e] = w;
}

__global__ __launch_bounds__(256, 2) void rvq_step(
    const float* __restrict__ x,
    const float* __restrict__ cbk,     // fp32 codebook k (phase 4)
    const u32x4* __restrict__ bpk,     // packed B frags for k: [12][64][64]
    const float* __restrict__ cnormk,  // N
    float* __restrict__ out0,          // B*K*D*L
    float* __restrict__ out1,          // B*L*K (float-encoded indices)
    int k)
{
    // A planes in fragment layout: xsh[plane][kg 0..15][l 0..63][8 bf16]
    __shared__ unsigned short xsh[3 * 16 * 64 * 8];     // 49152 B
    __shared__ unsigned long long keymin[4][64];        // 2048 B
    __shared__ int idx_final[64];

    const int tid = threadIdx.x;
    const int b  = blockIdx.x >> 6;
    const int l0 = (blockIdx.x & 63) * 64;
    const int ll = tid & 63;
    const int wv = tid >> 6;

    const float* prev = (k > 0) ? (out0 + ((size_t)b * KK + (k - 1)) * DD * LL) : nullptr;
    float* cur = out0 + ((size_t)b * KK + k) * DD * LL;
    const float* xb = x + (size_t)b * DD * LL;

    // ---- Phase 1: residual, bf16x3 split, write A planes to LDS ----
    {
        const int dg = wv;   // wave's 32-d quarter
#pragma unroll
        for (int g = 0; g < 4; ++g) {
            unsigned short h0[8], h1[8], h2[8];
#pragma unroll
            for (int j = 0; j < 8; ++j) {
                int d = dg * 32 + g * 8 + j;
                float v = xb[(size_t)d * LL + l0 + ll];
                if (k > 0) v -= prev[(size_t)d * LL + l0 + ll];
                unsigned short c0 = f2bf(v); float f0 = bf2f(c0);
                float r1 = v - f0;
                unsigned short c1 = f2bf(r1); float f1 = bf2f(c1);
                unsigned short c2 = f2bf(r1 - f1);
                h0[j] = c0; h1[j] = c1; h2[j] = c2;
            }
            const int kg = dg * 4 + g;
            u32x4 w0, w1, w2;
            w0.x = (unsigned)h0[0] | ((unsigned)h0[1] << 16);
            w0.y = (unsigned)h0[2] | ((unsigned)h0[3] << 16);
            w0.z = (unsigned)h0[4] | ((unsigned)h0[5] << 16);
            w0.w = (unsigned)h0[6] | ((unsigned)h0[7] << 16);
            w1.x = (unsigned)h1[0] | ((unsigned)h1[1] << 16);
            w1.y = (unsigned)h1[2] | ((unsigned)h1[3] << 16);
            w1.z = (unsigned)h1[4] | ((unsigned)h1[5] << 16);
            w1.w = (unsigned)h1[6] | ((unsigned)h1[7] << 16);
            w2.x = (unsigned)h2[0] | ((unsigned)h2[1] << 16);
            w2.y = (unsigned)h2[2] | ((unsigned)h2[3] << 16);
            w2.z = (unsigned)h2[4] | ((unsigned)h2[5] << 16);
            w2.w = (unsigned)h2[6] | ((unsigned)h2[7] << 16);
            *(u32x4*)(xsh + ((0 * 16 + kg) * 64 + ll) * 8) = w0;
            *(u32x4*)(xsh + ((1 * 16 + kg) * 64 + ll) * 8) = w1;
            *(u32x4*)(xsh + ((2 * 16 + kg) * 64 + ll) * 8) = w2;
        }
    }
    __syncthreads();

    // ---- Phase 2: 24 MFMA K-steps x (4 m-frags x 4 n-frags), per-wave 256 n ----
    const int lane = tid & 63;
    const int col  = lane & 15;
    const int quad = lane >> 4;

    // K-step tables: pass1 (a0,b0)(a1,b1)(a2,b0); pass2 (a0,b1)(a0,b2)(a1,b0)
    const int akg_t[24] = {0,4,8,12, 16,20,24,28, 32,36,40,44,
                           0,4,8,12, 0,4,8,12, 16,20,24,28};   // plane*16 + q*4
    const int bsl_t[24] = {0,1,2,3, 4,5,6,7, 0,1,2,3,
                           4,5,6,7, 8,9,10,11, 0,1,2,3};       // bplane*4 + q

    int lb[4];
#pragma unroll
    for (int i = 0; i < 4; ++i) lb[i] = (quad * 64 + i * 16 + col) * 8;  // shorts

    const u32x4* bl = bpk + lane;
    const int nfb = wv * 16;   // wave's base n-frag (256 n per wave)

    float minv[4][4];
    int   minn[4][4];
#pragma unroll
    for (int i = 0; i < 4; ++i)
#pragma unroll
        for (int r = 0; r < 4; ++r) { minv[i][r] = 3.4e38f; minn[i][r] = 0; }

    for (int ch = 0; ch < 4; ++ch) {
        f32x4 acc[4][4];
#pragma unroll
        for (int i = 0; i < 4; ++i)
#pragma unroll
            for (int j = 0; j < 4; ++j) acc[i][j] = (f32x4){0.f, 0.f, 0.f, 0.f};

        u32x4 ab[2][4], bb[2][4];
#pragma unroll
        for (int i = 0; i < 4; ++i)
            ab[0][i] = *(const u32x4*)(xsh + akg_t[0] * 512 + lb[i]);
#pragma unroll
        for (int j = 0; j < 4; ++j)
            bb[0][j] = bl[(size_t)(bsl_t[0] * 64 + nfb + ch * 4 + j) * 64];

#pragma unroll
        for (int t = 0; t < 24; ++t) {
            const int cu = t & 1, nx = cu ^ 1;
            if (t < 23) {
#pragma unroll
                for (int i = 0; i < 4; ++i)
                    ab[nx][i] = *(const u32x4*)(xsh + akg_t[t + 1] * 512 + lb[i]);
#pragma unroll
                for (int j = 0; j < 4; ++j)
                    bb[nx][j] = bl[(size_t)(bsl_t[t + 1] * 64 + nfb + ch * 4 + j) * 64];
            }
#pragma unroll
            for (int i = 0; i < 4; ++i) {
                bf16x8 av = __builtin_bit_cast(bf16x8, ab[cu][i]);
#pragma unroll
                for (int j = 0; j < 4; ++j) {
                    bf16x8 bv = __builtin_bit_cast(bf16x8, bb[cu][j]);
                    acc[i][j] = __builtin_amdgcn_mfma_f32_16x16x32_bf16(av, bv, acc[i][j], 0, 0, 0);
                }
            }
        }

        // epilogue: score = cnorm - 2*dot; running argmin.
        // C layout (m89-verified): col = lane&15, row = quad*4 + reg.
        const int nbase = wv * 256 + ch * 64;
#pragma unroll
        for (int j = 0; j < 4; ++j) {
            const int nn_ = nbase + j * 16 + col;
            const float cn = cnormk[nn_];
#pragma unroll
            for (int i = 0; i < 4; ++i)
#pragma unroll
                for (int r = 0; r < 4; ++r) {
                    float sc = cn - 2.0f * acc[i][j][r];
                    if (sc < minv[i][r]) { minv[i][r] = sc; minn[i][r] = nn_; }
                }
        }
    }

    // ---- Phase 3: argmin reduce: 16 col-lanes (shfl) then 4 waves (LDS) ----
    {
        unsigned long long key[4][4];
#pragma unroll
        for (int i = 0; i < 4; ++i)
#pragma unroll
            for (int r = 0; r < 4; ++r) {
                unsigned u = __float_as_uint(minv[i][r]);
                u = (u & 0x80000000u) ? ~u : (u | 0x80000000u);  // order-preserving
                key[i][r] = ((unsigned long long)u << 32) | (unsigned)minn[i][r];
            }
#pragma unroll
        for (int off = 1; off < 16; off <<= 1)
#pragma unroll
            for (int i = 0; i < 4; ++i)
#pragma unroll
                for (int r = 0; r < 4; ++r) {
                    unsigned long long o = __shfl_xor(key[i][r], off);
                    if (o < key[i][r]) key[i][r] = o;
                }
        if (col == 0) {
#pragma unroll
            for (int i = 0; i < 4; ++i)
#pragma unroll
                for (int r = 0; r < 4; ++r)
                    keymin[wv][i * 16 + quad * 4 + r] = key[i][r];
        }
    }
    __syncthreads();
    if (tid < 64) {
        unsigned long long kb = keymin[0][tid];
#pragma unroll
        for (int w = 1; w < 4; ++w) {
            unsigned long long kw = keymin[w][tid];
            if (kw < kb) kb = kw;
        }
        int n = (int)(kb & 0xFFFFFFFFu);
        idx_final[tid] = n;
        out1[((size_t)b * LL + l0 + tid) * KK + k] = (float)n;
    }
    __syncthreads();

    // ---- Phase 4: cumulative plane k = prev + cb[idx] (fp32, bit-exact) ----
    {
        const int d0 = tid >> 6;
        const int n = idx_final[ll];
        const float* crow = cbk + (size_t)n * DD;
#pragma unroll
        for (int i = 0; i < 32; ++i) {
            int d = d0 + i * 4;
            float p = (k > 0) ? prev[(size_t)d * LL + l0 + ll] : 0.f;
            cur[(size_t)d * LL + l0 + ll] = p + crow[d];
        }
    }
}

extern "C" void kernel_launch(void* const* d_in, const int* in_sizes, int n_in,
                              void* d_out, int out_size, void* d_ws, size_t ws_size,
                              hipStream_t stream) {
    const float* x  = (const float*)d_in[0];   // (B, D, L)
    const float* cb = (const float*)d_in[1];   // (K, N, D)
    float* out0 = (float*)d_out;                         // (B, K, D, L)
    float* out1 = out0 + (size_t)BB * KK * DD * LL;      // (B, L, K)

    u32x4* bpack = (u32x4*)d_ws;                         // 8*12*4096 entries = 6.0 MiB
    float* cnorm = (float*)((char*)d_ws + (size_t)8 * 12 * 4096 * 16);  // 32 KB

    pack_b<<<(8 * 12 * 4096) / 256, 256, 0, stream>>>(cb, bpack);
    cnorm_kernel<<<(KK * NN) / 256, 256, 0, stream>>>(cb, cnorm);
    for (int k = 0; k < KK; ++k) {
        rvq_step<<<BB * 64, 256, 0, stream>>>(
            x, cb + (size_t)k * NN * DD, bpack + (size_t)k * 12 * 4096,
            cnorm + (size_t)k * NN, out0, out1, k);
    }
}